// Round 1
// baseline (164.155 us; speedup 1.0000x reference)
//
#include <hip/hip_runtime.h>
#include <math.h>

// Siren: freq-encode [N,2] -> [N,48], then 48->32 (sin), 32->32 (sin), 32->1.
// Compute-bound fp32 baseline: 1 thread = 1 point, weights via scalar loads.

#define THREADS 256

__global__ __launch_bounds__(THREADS) void siren_fp32_kernel(
    const float2* __restrict__ x,
    const float* __restrict__ W0,   // [48][32] row-major
    const float* __restrict__ W1,   // [32][32] row-major
    const float* __restrict__ W2,   // [32]
    float* __restrict__ out,        // [N]
    int n)
{
    int i = blockIdx.x * blockDim.x + threadIdx.x;
    if (i >= n) return;

    const float2 p = x[i];
    constexpr float INV2PI = 0.15915494309189535f;

    float h[32];
#pragma unroll
    for (int c = 0; c < 32; ++c) h[c] = 0.0f;

    // ---- frequency encoding fused into layer 0 ----
    // enc layout: [sin(x0*f0..f11), cos(x0*f0..f11), sin(x1*f0..f11), cos(x1*f0..f11)]
    // sin(pi * 2^j * x) = sin(2*pi * frac(x * 2^(j-1)))
#pragma unroll
    for (int d = 0; d < 2; ++d) {
        float rev = (d == 0 ? p.x : p.y) * 0.5f;   // x * 2^-1  (j = 0)
#pragma unroll
        for (int j = 0; j < 12; ++j) {
            float r = __builtin_amdgcn_fractf(rev);
            float s = __builtin_amdgcn_sinf(r);     // sin(2*pi*r)
            float c = __builtin_amdgcn_cosf(r);
            const float* __restrict__ ws = W0 + (d * 24 + j) * 32;       // sin row
            const float* __restrict__ wc = W0 + (d * 24 + 12 + j) * 32;  // cos row
#pragma unroll
            for (int c2 = 0; c2 < 32; ++c2) h[c2] = fmaf(s, ws[c2], h[c2]);
#pragma unroll
            for (int c2 = 0; c2 < 32; ++c2) h[c2] = fmaf(c, wc[c2], h[c2]);
            rev *= 2.0f;                            // exact power-of-2 scaling
        }
    }

    // ---- sin activation (radians -> revolutions -> v_sin) ----
    float g[32];
#pragma unroll
    for (int c = 0; c < 32; ++c) {
        float r = __builtin_amdgcn_fractf(h[c] * INV2PI);
        g[c] = __builtin_amdgcn_sinf(r);
    }

    // ---- layer 1: 32 -> 32 ----
    float h1[32];
#pragma unroll
    for (int c = 0; c < 32; ++c) h1[c] = 0.0f;
#pragma unroll
    for (int k = 0; k < 32; ++k) {
        const float gk = g[k];
        const float* __restrict__ w = W1 + k * 32;
#pragma unroll
        for (int c = 0; c < 32; ++c) h1[c] = fmaf(gk, w[c], h1[c]);
    }

    // ---- sin activation + layer 2: 32 -> 1 ----
    float acc = 0.0f;
#pragma unroll
    for (int k = 0; k < 32; ++k) {
        float r = __builtin_amdgcn_fractf(h1[k] * INV2PI);
        acc = fmaf(__builtin_amdgcn_sinf(r), W2[k], acc);
    }

    out[i] = acc;
}

extern "C" void kernel_launch(void* const* d_in, const int* in_sizes, int n_in,
                              void* d_out, int out_size, void* d_ws, size_t ws_size,
                              hipStream_t stream) {
    const float2* x = (const float2*)d_in[0];
    const float* W0 = (const float*)d_in[1];
    const float* W1 = (const float*)d_in[2];
    const float* W2 = (const float*)d_in[3];
    float* out = (float*)d_out;

    const int n = in_sizes[0] / 2;  // x is [N,2]
    const int blocks = (n + THREADS - 1) / THREADS;
    siren_fp32_kernel<<<blocks, THREADS, 0, stream>>>(x, W0, W1, W2, out, n);
}

// Round 2
// 94.663 us; speedup vs baseline: 1.7341x; 1.7341x over previous
//
#include <hip/hip_runtime.h>
#include <hip/hip_bf16.h>
#include <math.h>

// Siren MLP, fully fused: enc(2->48) -> [48x32] sin -> [32x32] sin -> [32x1].
// One wave = 64 points. GEMMs on bf16 MFMA (16x16x32), K-slot permutation
// cancels between A (LDS reads) and B (pre-baked per-lane fragments in d_ws).

typedef short short8 __attribute__((ext_vector_type(8)));
typedef float f32x4 __attribute__((ext_vector_type(4)));

#define THREADS 256
#define WAVE_LDS 12288  // 8KB E-tile + 4KB H-tile

__device__ __forceinline__ unsigned packbf(float lo, float hi) {
    union { __hip_bfloat162 h; unsigned u; } v;
    v.h = __float22bfloat162_rn(make_float2(lo, hi));
    return v.u;
}

__device__ __forceinline__ float sinact(float h) {
    // sin(h), h in radians: v_sin takes revolutions
    float r = __builtin_amdgcn_fractf(h * 0.15915494309189535f);
    return __builtin_amdgcn_sinf(r);
}

// ---- setup kernel: bake per-lane B fragments into ws ----
// ws layout (uint4 units): [0..255]   W0 frags, frag id = s*2+n, [frag][lane]
//                          [256..383] W1 frags, frag id = 4+n
//                          [384..415] W2 as float2 per lane
__global__ void build_frags(const float* __restrict__ W0,
                            const float* __restrict__ W1,
                            const float* __restrict__ W2,
                            uint4* __restrict__ ws) {
    int l = threadIdx.x;
    if (l >= 64) return;
    int g = l >> 4, col = l & 15;

#pragma unroll
    for (int s = 0; s < 2; ++s) {
#pragma unroll
        for (int n = 0; n < 2; ++n) {
            unsigned w[4];
#pragma unroll
            for (int rp = 0; rp < 4; ++rp) {
                int r0 = 2 * rp, r1 = 2 * rp + 1;
                int k0 = 32 * s + 4 * g + (r0 & 3) + 16 * (r0 >> 2);
                int k1 = 32 * s + 4 * g + (r1 & 3) + 16 * (r1 >> 2);
                float lo = (k0 < 48) ? W0[k0 * 32 + 16 * n + col] : 0.0f;
                float hi = (k1 < 48) ? W0[k1 * 32 + 16 * n + col] : 0.0f;
                w[rp] = packbf(lo, hi);
            }
            ws[(s * 2 + n) * 64 + l] = make_uint4(w[0], w[1], w[2], w[3]);
        }
    }
#pragma unroll
    for (int n = 0; n < 2; ++n) {
        unsigned w[4];
#pragma unroll
        for (int rp = 0; rp < 4; ++rp) {
            int r0 = 2 * rp, r1 = 2 * rp + 1;
            int kp0 = 4 * g + (r0 & 3) + 16 * (r0 >> 2);
            int kp1 = 4 * g + (r1 & 3) + 16 * (r1 >> 2);
            // H-tile column interleave: col' = 2*(c&15) + (c>>4)  =>  c = (col'>>1) | ((col'&1)<<4)
            int c0 = (kp0 >> 1) | ((kp0 & 1) << 4);
            int c1 = (kp1 >> 1) | ((kp1 & 1) << 4);
            float lo = W1[c0 * 32 + 16 * n + col];
            float hi = W1[c1 * 32 + 16 * n + col];
            w[rp] = packbf(lo, hi);
        }
        ws[(4 + n) * 64 + l] = make_uint4(w[0], w[1], w[2], w[3]);
    }
    ((float2*)(ws + 384))[l] = make_float2(W2[col], W2[col + 16]);
}

__global__ __launch_bounds__(THREADS) void siren_mfma_kernel(
    const float2* __restrict__ x,
    const uint4* __restrict__ wf,
    float* __restrict__ out,
    int n)
{
    __shared__ __align__(16) char smem[4 * WAVE_LDS];
    const int lane = threadIdx.x & 63;
    const int wid = threadIdx.x >> 6;
    const int g = lane >> 4, c16 = lane & 15;
    const int p0 = blockIdx.x * THREADS + wid * 64;
    if (p0 >= n) return;

    char* E = smem + wid * WAVE_LDS;       // [64 rows][128B] swizzled bf16 enc tile
    char* H = E + 8192;                    // [64 rows][64B]  swizzled bf16 act tile

    // ---- weight fragments (per-lane constants, from ws) ----
    union U { uint4 u; short8 v; };
    short8 b0[2][2], b1[2];
#pragma unroll
    for (int s = 0; s < 2; ++s)
#pragma unroll
        for (int nn = 0; nn < 2; ++nn) { U t; t.u = wf[(s * 2 + nn) * 64 + lane]; b0[s][nn] = t.v; }
#pragma unroll
    for (int nn = 0; nn < 2; ++nn) { U t; t.u = wf[(4 + nn) * 64 + lane]; b1[nn] = t.v; }
    const float2 w2 = ((const float2*)(wf + 384))[lane];

    // ---- load point, frequency-encode (seeded double-angle recurrence) ----
    const float2 p = x[p0 + lane];
    unsigned P[24];
#pragma unroll
    for (int d = 0; d < 2; ++d) {
        const float xd = (d == 0) ? p.x : p.y;
        float sv[12], cv[12];
#pragma unroll
        for (int jb = 0; jb < 12; jb += 4) {
            const float scale = (jb == 0) ? 0.5f : (jb == 4) ? 8.0f : 128.0f;
            float r0 = __builtin_amdgcn_fractf(xd * scale);
            sv[jb] = __builtin_amdgcn_sinf(r0);   // sin(pi*2^jb*x)
            cv[jb] = __builtin_amdgcn_cosf(r0);
#pragma unroll
            for (int j = jb + 1; j < jb + 4; ++j) {
                float t = sv[j - 1] + sv[j - 1];
                sv[j] = t * cv[j - 1];
                cv[j] = fmaf(-t, sv[j - 1], 1.0f);
            }
        }
#pragma unroll
        for (int k2 = 0; k2 < 6; ++k2) P[d * 12 + k2]     = packbf(sv[2 * k2], sv[2 * k2 + 1]);
#pragma unroll
        for (int k2 = 0; k2 < 6; ++k2) P[d * 12 + 6 + k2] = packbf(cv[2 * k2], cv[2 * k2 + 1]);
    }

    // ---- write enc row to LDS (row = lane), XOR-swizzled chunks ----
    {
        char* Ew = E + lane * 128;
        const int swz = (lane & 7) << 4;
#pragma unroll
        for (int c = 0; c < 6; ++c)
            *(uint4*)(Ew + ((c * 16) ^ swz)) =
                make_uint4(P[4 * c], P[4 * c + 1], P[4 * c + 2], P[4 * c + 3]);
        *(uint4*)(Ew + (96 ^ swz))  = make_uint4(0, 0, 0, 0);   // K-pad 48..63 = 0
        *(uint4*)(Ew + (112 ^ swz)) = make_uint4(0, 0, 0, 0);
    }
    __syncthreads();

    // ---- layer 0: [64x64(pad)] @ [64x32] via 16 MFMA ----
    f32x4 acc[4][2];
#pragma unroll
    for (int m = 0; m < 4; ++m)
#pragma unroll
        for (int nn = 0; nn < 2; ++nn) acc[m][nn] = (f32x4){0.f, 0.f, 0.f, 0.f};

#pragma unroll
    for (int m = 0; m < 4; ++m) {
        const int row = 16 * m + c16;
        const char* Er = E + row * 128;
        const int sw = (row & 7) << 4;
#pragma unroll
        for (int s = 0; s < 2; ++s) {
            union { uint2 u[2]; short8 v; } fa;
            fa.u[0] = *(const uint2*)(Er + ((64 * s + 8 * g) ^ sw));
            fa.u[1] = *(const uint2*)(Er + ((64 * s + 8 * g + 32) ^ sw));
            acc[m][0] = __builtin_amdgcn_mfma_f32_16x16x32_bf16(fa.v, b0[s][0], acc[m][0], 0, 0, 0);
            acc[m][1] = __builtin_amdgcn_mfma_f32_16x16x32_bf16(fa.v, b0[s][1], acc[m][1], 0, 0, 0);
        }
    }

    // ---- sin activation, pack (n0,n1) channel pair, write H tile ----
#pragma unroll
    for (int m = 0; m < 4; ++m)
#pragma unroll
        for (int r = 0; r < 4; ++r) {
            float a0 = sinact(acc[m][0][r]);   // channel c16
            float a1 = sinact(acc[m][1][r]);   // channel 16+c16
            const int row = 16 * m + 4 * g + r;
            *(unsigned*)(H + row * 64 + ((4 * c16) ^ ((row & 3) << 4))) = packbf(a0, a1);
        }
    __syncthreads();

    // ---- layer 1: [64x32] @ [32x32] via 8 MFMA (k-permuted, cancels with b1) ----
    f32x4 acc1[4][2];
#pragma unroll
    for (int m = 0; m < 4; ++m)
#pragma unroll
        for (int nn = 0; nn < 2; ++nn) acc1[m][nn] = (f32x4){0.f, 0.f, 0.f, 0.f};

#pragma unroll
    for (int m = 0; m < 4; ++m) {
        const int row = 16 * m + c16;
        const char* Hr = H + row * 64;
        const int sw1 = (row & 3) << 4;
        union { uint2 u[2]; short8 v; } fa;
        fa.u[0] = *(const uint2*)(Hr + ((8 * g) ^ sw1));
        fa.u[1] = *(const uint2*)(Hr + ((8 * g + 32) ^ sw1));
        acc1[m][0] = __builtin_amdgcn_mfma_f32_16x16x32_bf16(fa.v, b1[0], acc1[m][0], 0, 0, 0);
        acc1[m][1] = __builtin_amdgcn_mfma_f32_16x16x32_bf16(fa.v, b1[1], acc1[m][1], 0, 0, 0);
    }

    // ---- sin activation + layer 2 partials ----
    float v[16];
#pragma unroll
    for (int m = 0; m < 4; ++m)
#pragma unroll
        for (int r = 0; r < 4; ++r) {
            float a0 = sinact(acc1[m][0][r]);
            float a1 = sinact(acc1[m][1][r]);
            v[4 * m + r] = fmaf(a0, w2.x, a1 * w2.y);
        }

    // ---- transpose-reduce across 16-lane group: lane i ends with idx=i sum ----
#pragma unroll
    for (int mask = 8; mask >= 1; mask >>= 1) {
        const bool hi = (lane & mask) != 0;
#pragma unroll
        for (int t = 0; t < mask; ++t) {
            float own = hi ? v[t + mask] : v[t];
            float snd = hi ? v[t] : v[t + mask];
            v[t] = own + __shfl_xor(snd, mask, 64);
        }
    }

    // lane holds out for row p = 16*(idx>>2) + 4*g + (idx&3), idx = lane&15
    const int pl = 16 * ((lane & 15) >> 2) + 4 * (lane >> 4) + (lane & 3);
    out[p0 + pl] = v[0];
}

extern "C" void kernel_launch(void* const* d_in, const int* in_sizes, int n_in,
                              void* d_out, int out_size, void* d_ws, size_t ws_size,
                              hipStream_t stream) {
    const float2* x = (const float2*)d_in[0];
    const float* W0 = (const float*)d_in[1];
    const float* W1 = (const float*)d_in[2];
    const float* W2 = (const float*)d_in[3];
    float* out = (float*)d_out;
    uint4* ws = (uint4*)d_ws;

    const int n = in_sizes[0] / 2;
    build_frags<<<1, 64, 0, stream>>>(W0, W1, W2, ws);
    const int blocks = (n + THREADS - 1) / THREADS;
    siren_mfma_kernel<<<blocks, THREADS, 0, stream>>>(x, ws, out, n);
}

// Round 3
// 50.182 us; speedup vs baseline: 3.2712x; 1.8864x over previous
//
#include <hip/hip_runtime.h>
#include <hip/hip_bf16.h>

// Siren fully fused, no E-tile: enc A-fragments computed directly in-lane
// (kappa slot map baked into B0), H-tile at 72B pitch (conflict-free, no
// swizzle), no barriers (per-wave LDS slices only).

typedef short short8 __attribute__((ext_vector_type(8)));
typedef float f32x4 __attribute__((ext_vector_type(4)));

#define THREADS 256
#define H_STRIDE 72
#define WAVE_LDS (64 * H_STRIDE)   // 4608 B per wave, 18432 B per block

__device__ __forceinline__ unsigned packbf(float lo, float hi) {
    union { __hip_bfloat162 h; unsigned u; } v;
    v.h = __float22bfloat162_rn(make_float2(lo, hi));
    return v.u;
}

__device__ __forceinline__ float sinact(float h) {
    float r = __builtin_amdgcn_fractf(h * 0.15915494309189535f);
    return __builtin_amdgcn_sinf(r);
}

// ---- bake per-lane B fragments ----
// ws (uint4): [0..255] W0 frags id=(s*2+n); [256..383] W1 frags id=4+n; [384..415] W2.
// W0 kappa(g,s,e): g -> (d = g&1, basej = 6*(g>>1));
//   s0: e0..5 = sin j=basej+e, e6..7 = cos j=basej+(e-6)
//   s1: e0..3 = cos j=basej+2+e, e4..7 = zero pad
__global__ void build_frags(const float* __restrict__ W0,
                            const float* __restrict__ W1,
                            const float* __restrict__ W2,
                            uint4* __restrict__ ws) {
    int l = threadIdx.x;
    if (l >= 64) return;
    int g = l >> 4, col = l & 15;
    int d = g & 1, basej = 6 * (g >> 1);

#pragma unroll
    for (int s = 0; s < 2; ++s)
#pragma unroll
        for (int n = 0; n < 2; ++n) {
            float ev[8];
#pragma unroll
            for (int e = 0; e < 8; ++e) {
                int k;
                if (s == 0) k = (e < 6) ? (d * 24 + basej + e) : (d * 24 + 12 + basej + e - 6);
                else        k = (e < 4) ? (d * 24 + 12 + basej + 2 + e) : -1;
                ev[e] = (k >= 0) ? W0[k * 32 + 16 * n + col] : 0.0f;
            }
            ws[(s * 2 + n) * 64 + l] = make_uint4(packbf(ev[0], ev[1]), packbf(ev[2], ev[3]),
                                                  packbf(ev[4], ev[5]), packbf(ev[6], ev[7]));
        }

    // W1: H u-slot p holds channel pair (p, p+16); lane reads u = {2g,2g+1,2g+8,2g+9}
#pragma unroll
    for (int n = 0; n < 2; ++n) {
        unsigned w[4];
#pragma unroll
        for (int rp = 0; rp < 4; ++rp) {
            int r0 = 2 * rp, r1 = 2 * rp + 1;
            int kp0 = 4 * g + (r0 & 3) + 16 * (r0 >> 2);
            int kp1 = 4 * g + (r1 & 3) + 16 * (r1 >> 2);
            int c0 = (kp0 >> 1) | ((kp0 & 1) << 4);
            int c1 = (kp1 >> 1) | ((kp1 & 1) << 4);
            w[rp] = packbf(W1[c0 * 32 + 16 * n + col], W1[c1 * 32 + 16 * n + col]);
        }
        ws[(4 + n) * 64 + l] = make_uint4(w[0], w[1], w[2], w[3]);
    }
    ((float2*)(ws + 384))[l] = make_float2(W2[col], W2[col + 16]);
}

__global__ __launch_bounds__(THREADS, 5) void siren_mfma_kernel(
    const float2* __restrict__ x,
    const uint4* __restrict__ wf,
    float* __restrict__ out,
    int n)
{
    __shared__ __align__(16) char smem[4 * WAVE_LDS];
    const int lane = threadIdx.x & 63;
    const int wid = threadIdx.x >> 6;
    const int g = lane >> 4, c16 = lane & 15;
    const int p0 = blockIdx.x * THREADS + wid * 64;
    if (p0 >= n) return;

    char* H = smem + wid * WAVE_LDS;

    // ---- weight fragments ----
    union U { uint4 u; short8 v; };
    short8 b0[2][2], b1[2];
#pragma unroll
    for (int s = 0; s < 2; ++s)
#pragma unroll
        for (int nn = 0; nn < 2; ++nn) { U t; t.u = wf[(s * 2 + nn) * 64 + lane]; b0[s][nn] = t.v; }
#pragma unroll
    for (int nn = 0; nn < 2; ++nn) { U t; t.u = wf[(4 + nn) * 64 + lane]; b1[nn] = t.v; }
    const float2 w2 = ((const float2*)(wf + 384))[lane];

    // ---- x for the 4 row blocks (broadcast within 16-lane column groups) ----
    float2 pm[4];
#pragma unroll
    for (int m = 0; m < 4; ++m) pm[m] = x[p0 + 16 * m + c16];

    const float sclseed = (g >> 1) ? 32.0f : 0.5f;  // 2^(basej-1), basej in {0,6}
    const bool dsel = (g & 1) != 0;

    // ---- layer 0: in-lane enc chains feeding MFMA directly ----
    f32x4 acc[4][2];
#pragma unroll
    for (int m = 0; m < 4; ++m)
#pragma unroll
        for (int nn = 0; nn < 2; ++nn) acc[m][nn] = (f32x4){0.f, 0.f, 0.f, 0.f};

#pragma unroll
    for (int m = 0; m < 4; ++m) {
        const float xd = dsel ? pm[m].y : pm[m].x;
        float sv[6], cv[6];
        float r0 = __builtin_amdgcn_fractf(xd * sclseed);
        sv[0] = __builtin_amdgcn_sinf(r0);
        cv[0] = __builtin_amdgcn_cosf(r0);
#pragma unroll
        for (int j = 1; j < 6; ++j) {
            float t = sv[j - 1] + sv[j - 1];
            sv[j] = t * cv[j - 1];
            cv[j] = fmaf(-t, sv[j - 1], 1.0f);
        }
        union { unsigned u[4]; short8 v; } a0, a1;
        a0.u[0] = packbf(sv[0], sv[1]); a0.u[1] = packbf(sv[2], sv[3]);
        a0.u[2] = packbf(sv[4], sv[5]); a0.u[3] = packbf(cv[0], cv[1]);
        a1.u[0] = packbf(cv[2], cv[3]); a1.u[1] = packbf(cv[4], cv[5]);
        a1.u[2] = 0; a1.u[3] = 0;
        acc[m][0] = __builtin_amdgcn_mfma_f32_16x16x32_bf16(a0.v, b0[0][0], acc[m][0], 0, 0, 0);
        acc[m][1] = __builtin_amdgcn_mfma_f32_16x16x32_bf16(a0.v, b0[0][1], acc[m][1], 0, 0, 0);
        acc[m][0] = __builtin_amdgcn_mfma_f32_16x16x32_bf16(a1.v, b0[1][0], acc[m][0], 0, 0, 0);
        acc[m][1] = __builtin_amdgcn_mfma_f32_16x16x32_bf16(a1.v, b0[1][1], acc[m][1], 0, 0, 0);
    }

    // ---- sin activation -> H tile (72B pitch, conflict-free) ----
#pragma unroll
    for (int m = 0; m < 4; ++m)
#pragma unroll
        for (int r = 0; r < 4; ++r) {
            const int row = 16 * m + 4 * g + r;
            *(unsigned*)(H + row * H_STRIDE + 4 * c16) =
                packbf(sinact(acc[m][0][r]), sinact(acc[m][1][r]));
        }

    // ---- layer 1 (same-wave LDS dependency, no barrier needed) ----
    f32x4 acc1[4][2];
#pragma unroll
    for (int m = 0; m < 4; ++m)
#pragma unroll
        for (int nn = 0; nn < 2; ++nn) acc1[m][nn] = (f32x4){0.f, 0.f, 0.f, 0.f};

#pragma unroll
    for (int m = 0; m < 4; ++m) {
        const char* Hr = H + (16 * m + c16) * H_STRIDE;
        union { uint2 u[2]; short8 v; } fa;
        fa.u[0] = *(const uint2*)(Hr + 8 * g);
        fa.u[1] = *(const uint2*)(Hr + 8 * g + 32);
        acc1[m][0] = __builtin_amdgcn_mfma_f32_16x16x32_bf16(fa.v, b1[0], acc1[m][0], 0, 0, 0);
        acc1[m][1] = __builtin_amdgcn_mfma_f32_16x16x32_bf16(fa.v, b1[1], acc1[m][1], 0, 0, 0);
    }

    // ---- sin activation + layer 2 partials ----
    float v[16];
#pragma unroll
    for (int m = 0; m < 4; ++m)
#pragma unroll
        for (int r = 0; r < 4; ++r) {
            float a0 = sinact(acc1[m][0][r]);
            float a1 = sinact(acc1[m][1][r]);
            v[4 * m + r] = fmaf(a0, w2.x, a1 * w2.y);
        }

    // ---- transpose-reduce across 16-lane group ----
#pragma unroll
    for (int mask = 8; mask >= 1; mask >>= 1) {
        const bool hi = (lane & mask) != 0;
#pragma unroll
        for (int t = 0; t < mask; ++t) {
            float own = hi ? v[t + mask] : v[t];
            float snd = hi ? v[t] : v[t + mask];
            v[t] = own + __shfl_xor(snd, mask, 64);
        }
    }

    const int pl = 16 * ((lane & 15) >> 2) + 4 * (lane >> 4) + (lane & 3);
    out[p0 + pl] = v[0];
}

extern "C" void kernel_launch(void* const* d_in, const int* in_sizes, int n_in,
                              void* d_out, int out_size, void* d_ws, size_t ws_size,
                              hipStream_t stream) {
    const float2* x = (const float2*)d_in[0];
    const float* W0 = (const float*)d_in[1];
    const float* W1 = (const float*)d_in[2];
    const float* W2 = (const float*)d_in[3];
    float* out = (float*)d_out;
    uint4* ws = (uint4*)d_ws;

    const int n = in_sizes[0] / 2;
    build_frags<<<1, 64, 0, stream>>>(W0, W1, W2, ws);
    const int blocks = (n + THREADS - 1) / THREADS;
    siren_mfma_kernel<<<blocks, THREADS, 0, stream>>>(x, ws, out, n);
}

// Round 4
// 40.587 us; speedup vs baseline: 4.0445x; 1.2364x over previous
//
#include <hip/hip_runtime.h>
#include <hip/hip_bf16.h>

// Siren fused, swapped-operand MFMA form: C = W^T @ data^T -> [chan][point].
// Per-m (16-point) pipeline keeps ~70 VGPRs live (no spills), H-tile plain
// [point][chan] at 80B pitch (b128-aligned, uniform banks), output reduce is
// 2 shuffles + coalesced store. Activation sin skips v_fract (HW range +-256 rev).

typedef short short8 __attribute__((ext_vector_type(8)));
typedef float f32x4 __attribute__((ext_vector_type(4)));

#define THREADS 256
#define H_STRIDE 80
#define WAVE_LDS (2 * 16 * H_STRIDE)   // 2560 B per wave (double-buffered 16 rows)

#define INV2PI 0.15915494309189535f

__device__ __forceinline__ unsigned packbf(float lo, float hi) {
    union { __hip_bfloat162 h; unsigned u; } v;
    v.h = __float22bfloat162_rn(make_float2(lo, hi));
    return v.u;
}

// sin(h radians). v_sin_f32 accepts revolutions in [-256, 256]; |h|/2pi <= ~1.3 here.
__device__ __forceinline__ float sinact(float h) {
    return __builtin_amdgcn_sinf(h * INV2PI);
}

// ---- bake per-lane A fragments (W^T) ----
// ws (uint4): [0..255]   W0^T frags, id = s*2+cb  (kappa0: same e-map as before)
//             [256..383] W1^T frags, id = 4+cb    (kappa1(g,e) = 8g+e)
//             [384..511] W2 per-lane float4 pair {W2[4g+r]}, {W2[16+4g+r]}
__global__ void build_frags(const float* __restrict__ W0,
                            const float* __restrict__ W1,
                            const float* __restrict__ W2,
                            uint4* __restrict__ ws) {
    int l = threadIdx.x;
    if (l >= 64) return;
    int g = l >> 4, c16 = l & 15;
    int d = g & 1, basej = 6 * (g >> 1);

#pragma unroll
    for (int s = 0; s < 2; ++s)
#pragma unroll
        for (int cb = 0; cb < 2; ++cb) {
            float ev[8];
#pragma unroll
            for (int e = 0; e < 8; ++e) {
                int k;
                if (s == 0) k = (e < 6) ? (d * 24 + basej + e) : (d * 24 + 12 + basej + e - 6);
                else        k = (e < 4) ? (d * 24 + 12 + basej + 2 + e) : -1;
                ev[e] = (k >= 0) ? W0[k * 32 + 16 * cb + c16] : 0.0f;   // A[i=c16][k] = W0[k][chan_out]
            }
            ws[(s * 2 + cb) * 64 + l] = make_uint4(packbf(ev[0], ev[1]), packbf(ev[2], ev[3]),
                                                   packbf(ev[4], ev[5]), packbf(ev[6], ev[7]));
        }

#pragma unroll
    for (int cb = 0; cb < 2; ++cb) {
        float ev[8];
#pragma unroll
        for (int e = 0; e < 8; ++e) ev[e] = W1[(8 * g + e) * 32 + 16 * cb + c16];
        ws[(4 + cb) * 64 + l] = make_uint4(packbf(ev[0], ev[1]), packbf(ev[2], ev[3]),
                                           packbf(ev[4], ev[5]), packbf(ev[6], ev[7]));
    }

    float4* w2v = (float4*)(ws + 384);
    w2v[2 * l]     = make_float4(W2[4 * g + 0], W2[4 * g + 1], W2[4 * g + 2], W2[4 * g + 3]);
    w2v[2 * l + 1] = make_float4(W2[16 + 4 * g + 0], W2[16 + 4 * g + 1],
                                 W2[16 + 4 * g + 2], W2[16 + 4 * g + 3]);
}

__global__ __launch_bounds__(THREADS, 5) void siren_mfma_kernel(
    const float2* __restrict__ x,
    const uint4* __restrict__ wf,
    float* __restrict__ out,
    int n)
{
    __shared__ __align__(16) char smem[4 * WAVE_LDS];
    const int lane = threadIdx.x & 63;
    const int wid = threadIdx.x >> 6;
    const int g = lane >> 4, c16 = lane & 15;
    const int p0 = blockIdx.x * THREADS + wid * 64;
    if (p0 >= n) return;

    char* H = smem + wid * WAVE_LDS;

    // ---- per-lane weight fragments ----
    union U { uint4 u; short8 v; };
    short8 a0[2][2], a1[2];
#pragma unroll
    for (int s = 0; s < 2; ++s)
#pragma unroll
        for (int cb = 0; cb < 2; ++cb) { U t; t.u = wf[(s * 2 + cb) * 64 + lane]; a0[s][cb] = t.v; }
#pragma unroll
    for (int cb = 0; cb < 2; ++cb) { U t; t.u = wf[(4 + cb) * 64 + lane]; a1[cb] = t.v; }
    const float4 w2a = ((const float4*)(wf + 384))[2 * lane];
    const float4 w2b = ((const float4*)(wf + 384))[2 * lane + 1];

    const float sclseed = (g >> 1) ? 32.0f : 0.5f;  // 2^(basej-1), basej in {0,6}
    const bool dsel = (g & 1) != 0;

    float v[4];

#pragma unroll
    for (int m = 0; m < 4; ++m) {
        // ---- enc chain for this lane's (d, j-range) slice of point 16m+c16 ----
        const float2 p = x[p0 + 16 * m + c16];
        const float xd = dsel ? p.y : p.x;
        float sv[6], cv[6];
        float r0 = __builtin_amdgcn_fractf(xd * sclseed);
        sv[0] = __builtin_amdgcn_sinf(r0);
        cv[0] = __builtin_amdgcn_cosf(r0);
#pragma unroll
        for (int j = 1; j < 6; ++j) {
            float t = sv[j - 1] + sv[j - 1];
            sv[j] = t * cv[j - 1];
            cv[j] = fmaf(-t, sv[j - 1], 1.0f);
        }
        union { unsigned u[4]; short8 v; } bs0, bs1;
        bs0.u[0] = packbf(sv[0], sv[1]); bs0.u[1] = packbf(sv[2], sv[3]);
        bs0.u[2] = packbf(sv[4], sv[5]); bs0.u[3] = packbf(cv[0], cv[1]);
        bs1.u[0] = packbf(cv[2], cv[3]); bs1.u[1] = packbf(cv[4], cv[5]);
        bs1.u[2] = 0; bs1.u[3] = 0;

        // ---- layer 0: C[chan][point] ----
        f32x4 acc[2] = {{0.f, 0.f, 0.f, 0.f}, {0.f, 0.f, 0.f, 0.f}};
        acc[0] = __builtin_amdgcn_mfma_f32_16x16x32_bf16(a0[0][0], bs0.v, acc[0], 0, 0, 0);
        acc[1] = __builtin_amdgcn_mfma_f32_16x16x32_bf16(a0[0][1], bs0.v, acc[1], 0, 0, 0);
        acc[0] = __builtin_amdgcn_mfma_f32_16x16x32_bf16(a0[1][0], bs1.v, acc[0], 0, 0, 0);
        acc[1] = __builtin_amdgcn_mfma_f32_16x16x32_bf16(a0[1][1], bs1.v, acc[1], 0, 0, 0);

        // ---- act -> H[point][chan], plain layout, double-buffered by m&1 ----
        char* Hb = H + (m & 1) * (16 * H_STRIDE);
#pragma unroll
        for (int cb = 0; cb < 2; ++cb) {
            unsigned u0 = packbf(sinact(acc[cb][0]), sinact(acc[cb][1]));
            unsigned u1 = packbf(sinact(acc[cb][2]), sinact(acc[cb][3]));
            *(uint2*)(Hb + c16 * H_STRIDE + 32 * cb + 8 * g) = make_uint2(u0, u1);
        }

        // ---- layer 1: B-frag = chans 8g..8g+7 of own point (one b128 read) ----
        union { uint4 u; short8 v; } fb;
        fb.u = *(const uint4*)(Hb + c16 * H_STRIDE + 16 * g);
        f32x4 acc1[2] = {{0.f, 0.f, 0.f, 0.f}, {0.f, 0.f, 0.f, 0.f}};
        acc1[0] = __builtin_amdgcn_mfma_f32_16x16x32_bf16(a1[0], fb.v, acc1[0], 0, 0, 0);
        acc1[1] = __builtin_amdgcn_mfma_f32_16x16x32_bf16(a1[1], fb.v, acc1[1], 0, 0, 0);

        // ---- act + W2 partial (chans 16cb+4g+r of point 16m+c16) ----
        float vm;
        vm = sinact(acc1[0][0]) * w2a.x;
        vm = fmaf(sinact(acc1[0][1]), w2a.y, vm);
        vm = fmaf(sinact(acc1[0][2]), w2a.z, vm);
        vm = fmaf(sinact(acc1[0][3]), w2a.w, vm);
        vm = fmaf(sinact(acc1[1][0]), w2b.x, vm);
        vm = fmaf(sinact(acc1[1][1]), w2b.y, vm);
        vm = fmaf(sinact(acc1[1][2]), w2b.z, vm);
        vm = fmaf(sinact(acc1[1][3]), w2b.w, vm);
        v[m] = vm;
    }

    // ---- reduce over g (4 lanes hold partials of the same point) ----
#pragma unroll
    for (int m = 0; m < 4; ++m) {
        v[m] += __shfl_xor(v[m], 16, 64);
        v[m] += __shfl_xor(v[m], 32, 64);
    }
    // lane's own output is m = g: point = 16g + c16 = lane
    float ra = (g & 1) ? v[1] : v[0];
    float rb = (g & 1) ? v[3] : v[2];
    out[p0 + lane] = (g & 2) ? rb : ra;
}

extern "C" void kernel_launch(void* const* d_in, const int* in_sizes, int n_in,
                              void* d_out, int out_size, void* d_ws, size_t ws_size,
                              hipStream_t stream) {
    const float2* x = (const float2*)d_in[0];
    const float* W0 = (const float*)d_in[1];
    const float* W1 = (const float*)d_in[2];
    const float* W2 = (const float*)d_in[3];
    float* out = (float*)d_out;
    uint4* ws = (uint4*)d_ws;

    const int n = in_sizes[0] / 2;
    build_frags<<<1, 64, 0, stream>>>(W0, W1, W2, ws);
    const int blocks = (n + THREADS - 1) / THREADS;
    siren_mfma_kernel<<<blocks, THREADS, 0, stream>>>(x, ws, out, n);
}